// Round 9
// baseline (475.166 us; speedup 1.0000x reference)
//
#include <hip/hip_runtime.h>
#include <math.h>

#define F_IN 256
#define HID  64
#define BSH  8              // bucket = dst >> 8 (256 nodes per bucket)
#define BSPAN 256
#define CHUNK 16384         // edges per sort block (64 per thread)
#define NBK_MAX 512

typedef __bf16   bf16x8 __attribute__((ext_vector_type(8)));
typedef float    floatx4 __attribute__((ext_vector_type(4)));
typedef _Float16 half8 __attribute__((ext_vector_type(8)));

// ---------------------------------------------------------------------------
// Pass 1: per-chunk histogram over coarse dst buckets
// ---------------------------------------------------------------------------
__global__ __launch_bounds__(256) void k_hist(const int* __restrict__ dst,
                                              int* __restrict__ cntT,
                                              int E, int NCH, int NBK) {
    __shared__ int hist[NBK_MAX];
    int t = threadIdx.x, c = blockIdx.x;
    hist[t] = 0; hist[t + 256] = 0;
    __syncthreads();
    int base = c * CHUNK;
#pragma unroll 4
    for (int j = 0; j < CHUNK / 256; j++) {
        int e = base + j * 256 + t;
        if (e < E) atomicAdd(&hist[dst[e] >> BSH], 1);
    }
    __syncthreads();
    for (int b = t; b < NBK; b += 256) cntT[b * NCH + c] = hist[b];
}

// ---------------------------------------------------------------------------
// Exclusive scan of cntT (S elements) -> off, plus sentinel off[S] = total
// ---------------------------------------------------------------------------
__global__ __launch_bounds__(256) void k_scanA(const int* __restrict__ cntT,
                                               int* __restrict__ off,
                                               int* __restrict__ partials, int S) {
    __shared__ int sh[256];
    int tid = threadIdx.x;
    int base = blockIdx.x * 1024 + tid * 4;
    int v[4];
    int s = 0;
#pragma unroll
    for (int j = 0; j < 4; j++) {
        int idx = base + j;
        v[j] = (idx < S) ? cntT[idx] : 0;
        s += v[j];
    }
    sh[tid] = s;
    __syncthreads();
    int mysum = s;
    for (int o = 1; o < 256; o <<= 1) {
        int tv = (tid >= o) ? sh[tid - o] : 0;
        __syncthreads();
        sh[tid] += tv;
        __syncthreads();
    }
    int pref = sh[tid] - mysum;
#pragma unroll
    for (int j = 0; j < 4; j++) {
        int idx = base + j;
        if (idx < S) off[idx] = pref;
        pref += v[j];
    }
    if (tid == 255) partials[blockIdx.x] = sh[255];
}

__global__ void k_scanB(int* __restrict__ partials, int* __restrict__ off,
                        int nblk, int S) {
    if (blockIdx.x == 0 && threadIdx.x == 0) {
        int run = 0;
        for (int b = 0; b < nblk; b++) { int t = partials[b]; partials[b] = run; run += t; }
        off[S] = run;   // == E
    }
}

__global__ void k_scanC(int* __restrict__ off, const int* __restrict__ partials, int S) {
    int i = blockIdx.x * blockDim.x + threadIdx.x;
    if (i < S) off[i] += partials[i >> 10];
}

// ---------------------------------------------------------------------------
// Pass 2: scatter edges into bucket-grouped ebuf. Entry = (src<<8)|(dst&255)
// ---------------------------------------------------------------------------
__global__ __launch_bounds__(256) void k_sortwrite(const int* __restrict__ src,
                                                   const int* __restrict__ dst,
                                                   const int* __restrict__ off,
                                                   int* __restrict__ ebuf,
                                                   int E, int NCH, int NBK) {
    __shared__ int cur[NBK_MAX];
    int t = threadIdx.x, c = blockIdx.x;
    for (int b = t; b < NBK; b += 256) cur[b] = off[b * NCH + c];
    __syncthreads();
    int base = c * CHUNK;
#pragma unroll 4
    for (int j = 0; j < CHUNK / 256; j++) {
        int e = base + j * 256 + t;
        if (e < E) {
            int s = src[e];
            int d = dst[e];
            int pos = atomicAdd(&cur[d >> BSH], 1);
            ebuf[pos] = (s << BSH) | (d & (BSPAN - 1));
        }
    }
}

// ---------------------------------------------------------------------------
// Pass 3: per-bucket node-level CSR: rp, dinv, node-sorted esrc
// ---------------------------------------------------------------------------
__global__ __launch_bounds__(256) void k_bucket_csr(const int* __restrict__ off,
                                                    const int* __restrict__ ebuf,
                                                    int* __restrict__ rp,
                                                    float* __restrict__ dinv,
                                                    int* __restrict__ esrc,
                                                    int N, int NCH, int NBK) {
    __shared__ int cnt[BSPAN];
    __shared__ int sh[BSPAN];
    int b = blockIdx.x, t = threadIdx.x;
    int base = off[b * NCH];
    int end  = off[(b + 1) * NCH];

    cnt[t] = 0;
    __syncthreads();
    for (int i = base + t; i < end; i += 256) atomicAdd(&cnt[ebuf[i] & (BSPAN - 1)], 1);
    __syncthreads();

    int c = cnt[t];
    sh[t] = c;
    __syncthreads();
    for (int o = 1; o < 256; o <<= 1) {
        int tv = (t >= o) ? sh[t - o] : 0;
        __syncthreads();
        sh[t] += tv;
        __syncthreads();
    }
    int excl = sh[t] - c;

    int node = (b << BSH) + t;
    if (node < N) {
        rp[node] = base + excl;
        dinv[node] = rsqrtf((float)(1 + c));
    }
    if (b == NBK - 1 && t == 0) rp[N] = end;
    __syncthreads();

    cnt[t] = base + excl;
    __syncthreads();
    for (int i = base + t; i < end; i += 256) {
        int v = ebuf[i];
        int p = atomicAdd(&cnt[v & (BSPAN - 1)], 1);
        esrc[p] = v >> BSH;
    }
}

// ---------------------------------------------------------------------------
// Weight prep: W[K x 64] -> split-bf16 MFMA FRAGMENT layout
//   Bf[c][ch2][lane][j] = W[ch2*32 + (lane>>4)*8 + j][c*16 + (lane&15)]
// ---------------------------------------------------------------------------
__global__ __launch_bounds__(256) void k_prepw(const float* __restrict__ W1,
                                               __bf16* __restrict__ f1h, __bf16* __restrict__ f1l,
                                               const float* __restrict__ W2,
                                               __bf16* __restrict__ f2h, __bf16* __restrict__ f2l) {
    int t = threadIdx.x + blockIdx.x * blockDim.x;   // 2048 threads
    for (int idx = t; idx < 16384; idx += 2048) {
        int j = idx & 7, lane = (idx >> 3) & 63, ch2 = (idx >> 9) & 7, c = idx >> 12;
        int k = ch2 * 32 + (lane >> 4) * 8 + j, col = c * 16 + (lane & 15);
        float w = W1[k * 64 + col];
        __bf16 h = (__bf16)w;
        f1h[idx] = h; f1l[idx] = (__bf16)(w - (float)h);
    }
    for (int idx = t; idx < 4096; idx += 2048) {
        int j = idx & 7, lane = (idx >> 3) & 63, ch2 = (idx >> 9) & 1, c = idx >> 10;
        int k = ch2 * 32 + (lane >> 4) * 8 + j, col = c * 16 + (lane & 15);
        float w = W2[k * 64 + col];
        __bf16 h = (__bf16)w;
        f2h[idx] = h; f2l[idx] = (__bf16)(w - (float)h);
    }
}

// ---------------------------------------------------------------------------
// GEMM1 (K=256, A fp32): m97-style LDS staging via global_load_lds(16B),
// double-buffered 64x64 chunks, seg-rotation swizzle. Output fp16.
//   D = Ah*Bh + Ah*Bl + Al*Bh;  C = D * dinv[row]  (fp16 store)
// ---------------------------------------------------------------------------
__global__ __launch_bounds__(256) void k_gemm1(const float* __restrict__ A,
                                               const __bf16* __restrict__ BfH,
                                               const __bf16* __restrict__ BfL,
                                               const float* __restrict__ dinv,
                                               _Float16* __restrict__ C, int nrows) {
    constexpr int K = 256, KC = 64, NCHK = 4, NCH32 = 8;
    __shared__ float As[2][64 * KC];       // 2 x 16 KB

    const int t = threadIdx.x;
    const int wave = t >> 6, lane = t & 63;
    const int m = lane & 15, q = lane >> 4;
    const int row0 = blockIdx.x * 64;

    const int s_sub = lane >> 4;
    const int s_seg = lane & 15;

    auto stage = [&](int ch, int buf) {
#pragma unroll
        for (int j = 0; j < 4; j++) {
            int lr = wave * 16 + j * 4 + s_sub;
            int gr = row0 + lr; if (gr > nrows - 1) gr = nrows - 1;
            int gs = (s_seg - lr) & 15;
            const float* g = A + (size_t)gr * K + ch * KC + gs * 4;
            float* l = &As[buf][(size_t)lr * KC + s_seg * 4];
            __builtin_amdgcn_global_load_lds(
                (const __attribute__((address_space(1))) void*)g,
                (__attribute__((address_space(3))) void*)l, 16, 0, 0);
        }
    };

    floatx4 acc[4] = {{0.f, 0.f, 0.f, 0.f}, {0.f, 0.f, 0.f, 0.f},
                      {0.f, 0.f, 0.f, 0.f}, {0.f, 0.f, 0.f, 0.f}};

    stage(0, 0);
    __syncthreads();

    for (int ch = 0; ch < NCHK; ch++) {
        if (ch + 1 < NCHK) stage(ch + 1, (ch + 1) & 1);

        const float* arow = &As[ch & 1][(size_t)(wave * 16 + m) * KC];
#pragma unroll
        for (int jj = 0; jj < 2; jj++) {
            int ch2 = ch * 2 + jj;
            int s0 = jj * 8 + q * 2;
            float4 v0 = *(const float4*)(arow + (((s0 + m) & 15) * 4));
            float4 v1 = *(const float4*)(arow + (((s0 + 1 + m) & 15) * 4));
            float af[8] = {v0.x, v0.y, v0.z, v0.w, v1.x, v1.y, v1.z, v1.w};
            bf16x8 ah, al;
#pragma unroll
            for (int j = 0; j < 8; j++) {
                __bf16 h = (__bf16)af[j];
                ah[j] = h;
                al[j] = (__bf16)(af[j] - (float)h);
            }
#pragma unroll
            for (int c = 0; c < 4; c++) {
                const bf16x8 bh = *(const bf16x8*)(BfH + ((size_t)(c * NCH32 + ch2) * 64 + lane) * 8);
                const bf16x8 bl = *(const bf16x8*)(BfL + ((size_t)(c * NCH32 + ch2) * 64 + lane) * 8);
                acc[c] = __builtin_amdgcn_mfma_f32_16x16x32_bf16(ah, bh, acc[c], 0, 0, 0);
                acc[c] = __builtin_amdgcn_mfma_f32_16x16x32_bf16(al, bh, acc[c], 0, 0, 0);
                acc[c] = __builtin_amdgcn_mfma_f32_16x16x32_bf16(ah, bl, acc[c], 0, 0, 0);
            }
        }
        __syncthreads();
    }

#pragma unroll
    for (int i = 0; i < 4; i++) {
        int r = row0 + wave * 16 + q * 4 + i;
        if (r < nrows) {
            float di = dinv[r];
#pragma unroll
            for (int c = 0; c < 4; c++)
                C[(size_t)r * 64 + c * 16 + m] = (_Float16)(acc[c][i] * di);
        }
    }
}

// ---------------------------------------------------------------------------
// FUSED agg(layer1) + GEMM2: block = 64 nodes.
// Phase 1: each wave aggregates 16 nodes (16-deep gather MLP over fp16 h1s),
//   v = relu(dinv[d]*(hs[d]+sum hs[src])+b1), written to seg-rotated LDS (fp32).
// Phase 2: MFMA h2 @ W2 from LDS (gemm1's proven read pattern), epilogue *dinv,
//   fp16 store of h2s.
// ---------------------------------------------------------------------------
__global__ __launch_bounds__(256) void k_aggemm(const _Float16* __restrict__ hs,
                                                const float* __restrict__ dinv,
                                                const int* __restrict__ rp,
                                                const int* __restrict__ esrc,
                                                const float* __restrict__ bias,
                                                const __bf16* __restrict__ BfH,
                                                const __bf16* __restrict__ BfL,
                                                _Float16* __restrict__ C, int n) {
    __shared__ float As[64 * 64];   // 16 KB, seg-rotated rows
    const int t = threadIdx.x;
    const int wave = t >> 6, lane = t & 63;
    const int m = lane & 15, q = lane >> 4;
    const int n0 = blockIdx.x * 64;
    const int seg = lane >> 2, off = lane & 3;
    const float bl = bias[lane];

    for (int i = 0; i < 16; i++) {
        int lr = wave * 16 + i;
        int nid = n0 + lr;
        int nn = min(nid, n - 1);
        float dii = dinv[nn];
        int e0 = rp[nn], e1 = rp[nn + 1];

        float a[16];
        a[0] = (float)hs[(size_t)nn * 64 + lane];
#pragma unroll
        for (int k2 = 1; k2 < 16; k2++) a[k2] = 0.f;

        for (int e = e0; e < e1; e += 16) {
            int last = e1 - 1;
#pragma unroll
            for (int k2 = 0; k2 < 16; k2++) {
                int idx = esrc[min(e + k2, last)];
                float v = (float)hs[(size_t)idx * 64 + lane];
                a[k2] += (e + k2 <= last) ? v : 0.f;
            }
        }
        float s = (((a[0] + a[1]) + (a[2] + a[3])) + ((a[4] + a[5]) + (a[6] + a[7])))
                + (((a[8] + a[9]) + (a[10] + a[11])) + ((a[12] + a[13]) + (a[14] + a[15])));
        float acc = fmaxf(s * dii + bl, 0.f);
        As[lr * 64 + (((seg + lr) & 15) << 2) + off] = (nid < n) ? acc : 0.f;
    }
    __syncthreads();

    floatx4 acc4[4] = {{0.f, 0.f, 0.f, 0.f}, {0.f, 0.f, 0.f, 0.f},
                       {0.f, 0.f, 0.f, 0.f}, {0.f, 0.f, 0.f, 0.f}};
    const float* arow = &As[(size_t)(wave * 16 + m) * 64];
#pragma unroll
    for (int jj = 0; jj < 2; jj++) {
        int s0 = jj * 8 + q * 2;
        float4 v0 = *(const float4*)(arow + (((s0 + m) & 15) * 4));
        float4 v1 = *(const float4*)(arow + (((s0 + 1 + m) & 15) * 4));
        float af[8] = {v0.x, v0.y, v0.z, v0.w, v1.x, v1.y, v1.z, v1.w};
        bf16x8 ah, al;
#pragma unroll
        for (int j = 0; j < 8; j++) {
            __bf16 h = (__bf16)af[j];
            ah[j] = h;
            al[j] = (__bf16)(af[j] - (float)h);
        }
#pragma unroll
        for (int c = 0; c < 4; c++) {
            const bf16x8 bh = *(const bf16x8*)(BfH + ((size_t)(c * 2 + jj) * 64 + lane) * 8);
            const bf16x8 bb = *(const bf16x8*)(BfL + ((size_t)(c * 2 + jj) * 64 + lane) * 8);
            acc4[c] = __builtin_amdgcn_mfma_f32_16x16x32_bf16(ah, bh, acc4[c], 0, 0, 0);
            acc4[c] = __builtin_amdgcn_mfma_f32_16x16x32_bf16(al, bh, acc4[c], 0, 0, 0);
            acc4[c] = __builtin_amdgcn_mfma_f32_16x16x32_bf16(ah, bb, acc4[c], 0, 0, 0);
        }
    }

#pragma unroll
    for (int i = 0; i < 4; i++) {
        int r = n0 + wave * 16 + q * 4 + i;
        if (r < n) {
            float di = dinv[r];
#pragma unroll
            for (int c = 0; c < 4; c++)
                C[(size_t)r * 64 + c * 16 + m] = (_Float16)(acc4[c][i] * di);
        }
    }
}

// ---------------------------------------------------------------------------
// agg(layer2) + fused W3: one wave per node, 16-deep gather MLP.
//   v = relu(dinv[d]*(h2s[d]+sum h2s[src])+b2);  h3[d] = (v @ W3) * dinv[d]
// ---------------------------------------------------------------------------
__global__ __launch_bounds__(256) void k_agg_w3(const _Float16* __restrict__ hs,
                                                const float* __restrict__ dinv,
                                                const int* __restrict__ rp,
                                                const int* __restrict__ esrc,
                                                const float* __restrict__ bias,
                                                const float* __restrict__ W3,
                                                float2* __restrict__ h3, int n) {
    int lane = threadIdx.x & 63;
    int nid = blockIdx.x * 4 + (threadIdx.x >> 6);
    if (nid >= n) return;
    nid = __builtin_amdgcn_readfirstlane(nid);

    float dii = dinv[nid];
    int e0 = rp[nid];
    int e1 = rp[nid + 1];

    float a[16];
    a[0] = (float)hs[(size_t)nid * 64 + lane];
#pragma unroll
    for (int k2 = 1; k2 < 16; k2++) a[k2] = 0.f;

    for (int e = e0; e < e1; e += 16) {
        int last = e1 - 1;
#pragma unroll
        for (int k2 = 0; k2 < 16; k2++) {
            int idx = esrc[min(e + k2, last)];
            float v = (float)hs[(size_t)idx * 64 + lane];
            a[k2] += (e + k2 <= last) ? v : 0.f;
        }
    }
    float s = (((a[0] + a[1]) + (a[2] + a[3])) + ((a[4] + a[5]) + (a[6] + a[7])))
            + (((a[8] + a[9]) + (a[10] + a[11])) + ((a[12] + a[13]) + (a[14] + a[15])));
    float acc = fmaxf(s * dii + bias[lane], 0.f);

    float2 w3 = ((const float2*)W3)[lane];
    float p0 = acc * w3.x;
    float p1 = acc * w3.y;
#pragma unroll
    for (int o = 32; o > 0; o >>= 1) {
        p0 += __shfl_xor(p0, o, 64);
        p1 += __shfl_xor(p1, o, 64);
    }
    if (lane == 0) h3[nid] = make_float2(p0 * dii, p1 * dii);
}

// ---------------------------------------------------------------------------
// Final layer: wave-per-node, EDGE-PARALLEL aggregation (lane e gathers edge e)
// + bias + log_softmax. h3s rows already *dinv.
// ---------------------------------------------------------------------------
__global__ __launch_bounds__(256) void k_final(const float2* __restrict__ h3s,
                                               const float* __restrict__ dinv,
                                               const int* __restrict__ rp,
                                               const int* __restrict__ esrc,
                                               const float* __restrict__ b3,
                                               float* __restrict__ out, int n) {
    int lane = threadIdx.x & 63;
    int nid = blockIdx.x * 4 + (threadIdx.x >> 6);
    if (nid >= n) return;
    nid = __builtin_amdgcn_readfirstlane(nid);

    int e0 = rp[nid], e1 = rp[nid + 1];
    float ax = 0.f, ay = 0.f;
    for (int e = e0; e < e1; e += 64) {
        int idx = e + lane;
        int s = esrc[min(idx, e1 - 1)];
        float2 v = h3s[s];
        bool valid = idx < e1;
        ax += valid ? v.x : 0.f;
        ay += valid ? v.y : 0.f;
    }
#pragma unroll
    for (int o = 32; o > 0; o >>= 1) {
        ax += __shfl_xor(ax, o, 64);
        ay += __shfl_xor(ay, o, 64);
    }
    if (lane == 0) {
        float dii = dinv[nid];
        float2 h = h3s[nid];
        float l0 = (h.x + ax) * dii + b3[0];
        float l1 = (h.y + ay) * dii + b3[1];
        float m = fmaxf(l0, l1);
        float lse = m + logf(expf(l0 - m) + expf(l1 - m));
        ((float2*)out)[nid] = make_float2(l0 - lse, l1 - lse);
    }
}

// ---------------------------------------------------------------------------
// Launch
// ---------------------------------------------------------------------------
extern "C" void kernel_launch(void* const* d_in, const int* in_sizes, int n_in,
                              void* d_out, int out_size, void* d_ws, size_t ws_size,
                              hipStream_t stream) {
    const float* x   = (const float*)d_in[0];
    const int*   ei  = (const int*)d_in[1];
    const float* W1  = (const float*)d_in[2];
    const float* b1  = (const float*)d_in[3];
    const float* W2  = (const float*)d_in[4];
    const float* b2  = (const float*)d_in[5];
    const float* W3  = (const float*)d_in[6];
    const float* b3  = (const float*)d_in[7];
    float* out = (float*)d_out;

    const int N = in_sizes[0] / F_IN;   // 100000
    const int E = in_sizes[1] / 2;      // 1600000
    const int* src = ei;
    const int* dst = ei + E;

    const int NBK = (N + BSPAN - 1) / BSPAN;      // 391
    const int NCH = (E + CHUNK - 1) / CHUNK;      // 98
    const int S   = NBK * NCH;

    // workspace bump allocator (256B aligned)
    char* p = (char*)d_ws;
    auto alloc = [&](size_t bytes) -> void* {
        void* r = (void*)p;
        p += (bytes + 255) & ~(size_t)255;
        return r;
    };
    int*      cntT     = (int*)alloc((size_t)S * 4);
    int*      off      = (int*)alloc((size_t)(S + 1) * 4);
    int*      partials = (int*)alloc(4096);
    int*      ebuf     = (int*)alloc((size_t)E * 4);
    int*      esrc     = (int*)alloc((size_t)E * 4);
    int*      rp       = (int*)alloc((size_t)(N + 1) * 4);
    float*    dinv     = (float*)alloc((size_t)N * 4);
    _Float16* bufA     = (_Float16*)alloc((size_t)N * HID * 2);
    _Float16* bufB     = (_Float16*)alloc((size_t)N * HID * 2);
    float*    h3       = (float*)alloc((size_t)N * 2 * 4);
    __bf16*   f1h      = (__bf16*)alloc(16384 * 2);
    __bf16*   f1l      = (__bf16*)alloc(16384 * 2);
    __bf16*   f2h      = (__bf16*)alloc(4096 * 2);
    __bf16*   f2l      = (__bf16*)alloc(4096 * 2);

    const int T = 256;
    int scanBlocks = (S + 1023) / 1024;

    // weight prep (independent of CSR chain)
    k_prepw<<<8, T, 0, stream>>>(W1, f1h, f1l, W2, f2h, f2l);

    // CSR build via locality-aware counting sort
    k_hist<<<NCH, T, 0, stream>>>(dst, cntT, E, NCH, NBK);
    k_scanA<<<scanBlocks, T, 0, stream>>>(cntT, off, partials, S);
    k_scanB<<<1, 64, 0, stream>>>(partials, off, scanBlocks, S);
    k_scanC<<<(S + T - 1) / T, T, 0, stream>>>(off, partials, S);
    k_sortwrite<<<NCH, T, 0, stream>>>(src, dst, off, ebuf, E, NCH, NBK);
    k_bucket_csr<<<NBK, T, 0, stream>>>(off, ebuf, rp, dinv, esrc, N, NCH, NBK);

    // layer 1 GEMM
    int gemmBlocks = (N + 63) / 64;
    k_gemm1<<<gemmBlocks, T, 0, stream>>>(x, f1h, f1l, dinv, bufA, N);

    // fused: agg(layer1) + GEMM2 -> h2s (fp16)
    k_aggemm<<<gemmBlocks, T, 0, stream>>>(bufA, dinv, rp, esrc, b1, f2h, f2l, bufB, N);

    // agg(layer2) + fused W3 -> h3 (float2)
    k_agg_w3<<<(N + 3) / 4, T, 0, stream>>>(bufB, dinv, rp, esrc, b2, W3, (float2*)h3, N);

    // layer 3 + log_softmax (edge-parallel)
    k_final<<<(N + 3) / 4, T, 0, stream>>>((const float2*)h3, dinv, rp, esrc, b3, out, N);
}